// Round 2
// baseline (11275.664 us; speedup 1.0000x reference)
//
#include <hip/hip_runtime.h>
#include <hip/hip_bf16.h>

// All tensors fp32 (reference setup_inputs is jnp.float32).

// ---------------- workspace layout (float offsets), ~114.6 MB ----------------
static constexpr size_t OFF_P = 0;              // 256x256x8x8 residual stream A
static constexpr size_t OFF_Q = 4194304;        // residual stream B
static constexpr size_t OFF_H1 = 8388608;       // 256x256x16x16 activation
static constexpr size_t OFF_WT2 = 25165824;     // enc_w2^T [k=4096][oc=256]
static constexpr size_t OFF_WT3 = 26214400;     // 4x res conv3^T [k=2304][oc=256]
static constexpr size_t OFF_WT1 = 28573696;     // 4x res conv1^T [k=256][oc=256]
static constexpr size_t OFF_WTD1 = 28835840;    // dec_w1 [ic*16+kyx][oc=256]
static constexpr size_t OFF_WTD2 = 29884416;    // dec_w2 [ic][kyx][oc=3]
static constexpr size_t OFF_EMBT = 29896704;    // embedding^T [c=256][e=512]
static constexpr size_t OFF_ENORM = 30027776;   // |e|^2 per code (512)
static constexpr size_t OFF_RS = 30028288;      // per-sample rsqrt (256)
static constexpr size_t OFF_ACC = 30028544;     // [0]=sse_vq, [1]=sse_rec

// ---------------- weight prep ----------------
// batched transpose: src[b][oc][k] -> dst[b][k][oc]
__global__ void k_transpose(const float* __restrict__ src, float* __restrict__ dst,
                            int OC, int K, int total) {
  int i = blockIdx.x * 256 + threadIdx.x;
  if (i >= total) return;
  int bk = OC * K;
  int b = i / bk;
  int r = i - b * bk;
  int oc = r / K;
  int k = r - oc * K;
  dst[(size_t)b * bk + (size_t)k * OC + oc] = src[i];
}

// dec_w1 (ic,oc,ky,kx) -> [ic*16+kyx][oc]
__global__ void k_transpose_dec1(const float* __restrict__ src, float* __restrict__ dst) {
  int i = blockIdx.x * 256 + threadIdx.x;  // 1048576
  int kyx = i & 15;
  int oc = (i >> 4) & 255;
  int ic = i >> 12;
  dst[(ic * 16 + kyx) * 256 + oc] = src[i];
}

// dec_w2 (ic=256, oc=3, ky, kx) -> [ic][kyx][oc]
__global__ void k_prep_dec2(const float* __restrict__ src, float* __restrict__ dst) {
  int i = blockIdx.x * 256 + threadIdx.x;
  if (i >= 12288) return;
  int kyx = i & 15;
  int r = i >> 4;
  int oc = r % 3;
  int ic = r / 3;
  dst[(ic * 16 + kyx) * 3 + oc] = src[i];
}

__global__ void k_enorm(const float* __restrict__ emb, float* __restrict__ enorm) {
  int e = blockIdx.x * 64 + threadIdx.x;
  if (e >= 512) return;
  float s = 0.f;
  for (int c = 0; c < 256; ++c) {
    float v = emb[e * 256 + c];
    s += v * v;
  }
  enorm[e] = s;
}

__global__ void k_zero2(float* __restrict__ p) {
  if (threadIdx.x < 2) p[threadIdx.x] = 0.f;
}

// ---------------- encoder conv1: 3->256, k4 s2 p1, 32->16, relu ----------------
__global__ void __launch_bounds__(256) k_conv1(const float* __restrict__ x,
                                               const float* __restrict__ w,
                                               const float* __restrict__ bias,
                                               float* __restrict__ out) {
  int i = blockIdx.x * 256 + threadIdx.x;  // 16777216
  int ox = i & 15, oy = (i >> 4) & 15, oc = (i >> 8) & 255, n = i >> 16;
  float acc = bias[oc];
  for (int ic = 0; ic < 3; ++ic) {
#pragma unroll
    for (int ky = 0; ky < 4; ++ky) {
      int iy = 2 * oy - 1 + ky;
      if ((unsigned)iy >= 32u) continue;
#pragma unroll
      for (int kx = 0; kx < 4; ++kx) {
        int ix = 2 * ox - 1 + kx;
        if ((unsigned)ix >= 32u) continue;
        acc += x[((n * 3 + ic) * 32 + iy) * 32 + ix] *
               w[((oc * 3 + ic) * 4 + ky) * 4 + kx];
      }
    }
  }
  out[i] = fmaxf(acc, 0.f);
}

// ---------------- encoder conv2: 256->256, k4 s2 p1, 16->8, relu ----------------
__global__ void __launch_bounds__(256) k_conv2(const float* __restrict__ in,
                                               const float* __restrict__ wT,
                                               const float* __restrict__ bias,
                                               float* __restrict__ out) {
  __shared__ float patch[4096];
  int blk = blockIdx.x;  // 16384 = n*64 + oy*8 + ox
  int ox = blk & 7, oy = (blk >> 3) & 7, n = blk >> 6;
  int t = threadIdx.x;
  for (int j = t; j < 4096; j += 256) {
    int kx = j & 3, ky = (j >> 2) & 3, ic = j >> 4;
    int iy = 2 * oy - 1 + ky, ix = 2 * ox - 1 + kx;
    patch[j] = ((unsigned)iy < 16u && (unsigned)ix < 16u)
                   ? in[((n * 256 + ic) * 16 + iy) * 16 + ix]
                   : 0.f;
  }
  __syncthreads();
  const float* wp = wT + t;
  float a0 = bias[t], a1 = 0.f, a2 = 0.f, a3 = 0.f;
#pragma unroll 4
  for (int j = 0; j < 4096; j += 4) {
    a0 += patch[j + 0] * wp[(j + 0) * 256];
    a1 += patch[j + 1] * wp[(j + 1) * 256];
    a2 += patch[j + 2] * wp[(j + 2) * 256];
    a3 += patch[j + 3] * wp[(j + 3) * 256];
  }
  out[((n * 256 + t) * 8 + oy) * 8 + ox] = fmaxf((a0 + a1) + (a2 + a3), 0.f);
}

// ---------------- per-sample rms: rs[n] = rsqrt(mean(x^2)+eps) ----------------
__global__ void __launch_bounds__(256) k_rms(const float* __restrict__ x, float* __restrict__ rs) {
  __shared__ float sd[256];
  int n = blockIdx.x, t = threadIdx.x;
  const float* p = x + (size_t)n * 16384;
  float s = 0.f;
  for (int i = t; i < 16384; i += 256) {
    float v = p[i];
    s += v * v;
  }
  sd[t] = s;
  __syncthreads();
  for (int k = 128; k > 0; k >>= 1) {
    if (t < k) sd[t] += sd[t + k];
    __syncthreads();
  }
  if (t == 0) rs[n] = 1.0f / sqrtf(sd[0] / 16384.f + 1.1920929e-07f);
}

// ---------------- res conv3x3 (rmsnorm fused into staging), out = in + relu(conv) ----------------
__global__ void __launch_bounds__(256) k_res3(const float* __restrict__ in,
                                              const float* __restrict__ rs,
                                              const float* __restrict__ rmsw,
                                              const float* __restrict__ wT,
                                              const float* __restrict__ bias,
                                              float* __restrict__ out) {
  __shared__ float patch[2304];
  int blk = blockIdx.x;
  int ox = blk & 7, oy = (blk >> 3) & 7, n = blk >> 6;
  int t = threadIdx.x;
  float scale = rs[n];
  for (int j = t; j < 2304; j += 256) {
    int ic = j / 9;
    int r = j - ic * 9;
    int ky = r / 3, kx = r - ky * 3;
    int iy = oy - 1 + ky, ix = ox - 1 + kx;
    patch[j] = ((unsigned)iy < 8u && (unsigned)ix < 8u)
                   ? in[((n * 256 + ic) * 8 + iy) * 8 + ix] * scale *
                         rmsw[(ic * 8 + iy) * 8 + ix]
                   : 0.f;
  }
  __syncthreads();
  const float* wp = wT + t;
  float a0 = bias[t], a1 = 0.f, a2 = 0.f, a3 = 0.f;
#pragma unroll 4
  for (int j = 0; j < 2304; j += 4) {
    a0 += patch[j + 0] * wp[(j + 0) * 256];
    a1 += patch[j + 1] * wp[(j + 1) * 256];
    a2 += patch[j + 2] * wp[(j + 2) * 256];
    a3 += patch[j + 3] * wp[(j + 3) * 256];
  }
  int o = ((n * 256 + t) * 8 + oy) * 8 + ox;
  out[o] = in[o] + fmaxf((a0 + a1) + (a2 + a3), 0.f);
}

// ---------------- res conv1x1 (rmsnorm fused), out = in + relu(conv) ----------------
__global__ void __launch_bounds__(256) k_res1(const float* __restrict__ in,
                                              const float* __restrict__ rs,
                                              const float* __restrict__ rmsw,
                                              const float* __restrict__ wT,
                                              const float* __restrict__ bias,
                                              float* __restrict__ out) {
  __shared__ float patch[256];
  int blk = blockIdx.x;
  int ox = blk & 7, oy = (blk >> 3) & 7, n = blk >> 6;
  int t = threadIdx.x;
  float scale = rs[n];
  patch[t] = in[((n * 256 + t) * 8 + oy) * 8 + ox] * scale * rmsw[(t * 8 + oy) * 8 + ox];
  __syncthreads();
  const float* wp = wT + t;
  float a0 = bias[t], a1 = 0.f, a2 = 0.f, a3 = 0.f;
#pragma unroll 4
  for (int j = 0; j < 256; j += 4) {
    a0 += patch[j + 0] * wp[(j + 0) * 256];
    a1 += patch[j + 1] * wp[(j + 1) * 256];
    a2 += patch[j + 2] * wp[(j + 2) * 256];
    a3 += patch[j + 3] * wp[(j + 3) * 256];
  }
  int o = ((n * 256 + t) * 8 + oy) * 8 + ox;
  out[o] = in[o] + fmaxf((a0 + a1) + (a2 + a3), 0.f);
}

// ---------------- VQ: argmin over 512 codes, q out, sse accumulate ----------------
__global__ void __launch_bounds__(256) k_vq(const float* __restrict__ enc,
                                            const float* __restrict__ embT,
                                            const float* __restrict__ emb,
                                            const float* __restrict__ enorm,
                                            float* __restrict__ q, float* __restrict__ sse) {
  __shared__ float z[256];
  __shared__ float sd[256];
  __shared__ int si[256];
  int tkn = blockIdx.x;  // n*64 + h*8 + w
  int w = tkn & 7, h = (tkn >> 3) & 7, n = tkn >> 6;
  int t = threadIdx.x;
  z[t] = enc[((n * 256 + t) * 8 + h) * 8 + w];
  __syncthreads();
  float d0 = 0.f, d1 = 0.f;
  const float* p0 = embT + t;
  const float* p1 = embT + t + 256;
#pragma unroll 8
  for (int c = 0; c < 256; ++c) {
    float zv = z[c];
    d0 += zv * p0[c * 512];
    d1 += zv * p1[c * 512];
  }
  float s0 = enorm[t] - 2.f * d0;
  float s1 = enorm[t + 256] - 2.f * d1;
  float best;
  int bi;
  if (s1 < s0) { best = s1; bi = t + 256; } else { best = s0; bi = t; }
  sd[t] = best;
  si[t] = bi;
  __syncthreads();
  for (int k = 128; k > 0; k >>= 1) {
    if (t < k) {
      float o = sd[t + k];
      int oi = si[t + k];
      if (o < sd[t] || (o == sd[t] && oi < si[t])) { sd[t] = o; si[t] = oi; }
    }
    __syncthreads();
  }
  int idx = si[0];
  float qv = emb[idx * 256 + t];
  q[((n * 256 + t) * 8 + h) * 8 + w] = qv;
  float d = z[t] - qv;
  __syncthreads();
  sd[t] = d * d;
  __syncthreads();
  for (int k = 128; k > 0; k >>= 1) {
    if (t < k) sd[t] += sd[t + k];
    __syncthreads();
  }
  if (t == 0) atomicAdd(sse, sd[0]);
}

// ---------------- deconv1: ConvTranspose 256->256 k4 s2 p1, 8->16, relu ----------------
__global__ void __launch_bounds__(256) k_deconv1(const float* __restrict__ in,
                                                 const float* __restrict__ wT,
                                                 const float* __restrict__ bias,
                                                 float* __restrict__ out) {
  __shared__ float patch[1024];
  int blk = blockIdx.x;  // 65536 = n*256 + oy*16 + ox
  int ox = blk & 15, oy = (blk >> 4) & 15, n = blk >> 8;
  int t = threadIdx.x;
  int py = (oy + 1) & 1, px = (ox + 1) & 1;
  int dy = (oy + 1 - py) >> 1, dx = (ox + 1 - px) >> 1;
  for (int j = t; j < 1024; j += 256) {
    int sx = j & 1, s = (j >> 1) & 1, ic = j >> 2;
    int iy = dy - 1 + s, ix = dx - 1 + sx;
    patch[j] = ((unsigned)iy < 8u && (unsigned)ix < 8u)
                   ? in[((n * 256 + ic) * 8 + iy) * 8 + ix]
                   : 0.f;
  }
  __syncthreads();
  // tap -> kernel: (s,sx)=(0,0): ky=py+2,kx=px+2 ; (0,1): kx=px ; (1,0): ky=py ; (1,1)
  int k00 = ((py + 2) * 4 + px + 2) * 256;
  int k01 = k00 - 2 * 256;
  int k10 = (py * 4 + px + 2) * 256;
  int k11 = k10 - 2 * 256;
  const float* wp = wT + t;
  float a0 = bias[t], a1 = 0.f, a2 = 0.f, a3 = 0.f;
#pragma unroll 4
  for (int ic = 0; ic < 256; ++ic) {
    const float* pp = patch + ic * 4;
    const float* ww = wp + ic * 4096;
    a0 += pp[0] * ww[k00];
    a1 += pp[1] * ww[k01];
    a2 += pp[2] * ww[k10];
    a3 += pp[3] * ww[k11];
  }
  out[((n * 256 + t) * 16 + oy) * 16 + ox] = fmaxf((a0 + a1) + (a2 + a3), 0.f);
}

// ---------------- deconv2: ConvTranspose 256->3, 16->32, + reconst loss ----------------
__global__ void __launch_bounds__(256) k_deconv2(const float* __restrict__ in,
                                                 const float* __restrict__ wT,
                                                 const float* __restrict__ bias,
                                                 const float* __restrict__ x,
                                                 float* __restrict__ dec,
                                                 float* __restrict__ sse) {
  __shared__ float patch[9216];  // [ic=256][s=2][col=18] (col = ix+1, ix in [-1,16])
  __shared__ float red[768];
  int blk = blockIdx.x;  // 8192 = n*32 + oy
  int oy = blk & 31, n = blk >> 5;
  int t = threadIdx.x;
  int py = (oy + 1) & 1;
  int dy = (oy + 1 - py) >> 1;
  for (int j = t; j < 9216; j += 256) {
    int col = j % 18;
    int r = j / 18;
    int s = r & 1, ic = r >> 1;
    int ix = col - 1, iy = dy - 1 + s;
    patch[j] = ((unsigned)iy < 16u && (unsigned)ix < 16u)
                   ? in[((n * 256 + ic) * 16 + iy) * 16 + ix]
                   : 0.f;
  }
  __syncthreads();
  int ox = t & 31, g = t >> 5;  // g: ic group of 32
  int px = (ox + 1) & 1;
  int dx = (ox + 1 - px) >> 1;
  int k00 = ((py + 2) * 4 + px + 2) * 3;
  int k01 = k00 - 6;
  int k10 = (py * 4 + px + 2) * 3;
  int k11 = k10 - 6;
  float a0 = 0.f, a1 = 0.f, a2 = 0.f;
  for (int ic = g * 32; ic < g * 32 + 32; ++ic) {
    const float* pp = patch + ic * 36;
    float v00 = pp[dx], v01 = pp[dx + 1], v10 = pp[18 + dx], v11 = pp[18 + dx + 1];
    const float* ww = wT + ic * 48;
    a0 += v00 * ww[k00 + 0] + v01 * ww[k01 + 0] + v10 * ww[k10 + 0] + v11 * ww[k11 + 0];
    a1 += v00 * ww[k00 + 1] + v01 * ww[k01 + 1] + v10 * ww[k10 + 1] + v11 * ww[k11 + 1];
    a2 += v00 * ww[k00 + 2] + v01 * ww[k01 + 2] + v10 * ww[k10 + 2] + v11 * ww[k11 + 2];
  }
  red[t * 3 + 0] = a0;
  red[t * 3 + 1] = a1;
  red[t * 3 + 2] = a2;
  __syncthreads();
  float sq = 0.f;
  if (t < 96) {
    int ox2 = t & 31, oc = t >> 5;
    float v = bias[oc];
#pragma unroll
    for (int g2 = 0; g2 < 8; ++g2) v += red[(g2 * 32 + ox2) * 3 + oc];
    int oi = ((n * 3 + oc) * 32 + oy) * 32 + ox2;
    dec[oi] = v;
    float d = v - x[oi];
    sq = d * d;
  }
  __syncthreads();
  red[t] = sq;
  __syncthreads();
  for (int k = 128; k > 0; k >>= 1) {
    if (t < k) red[t] += red[t + k];
    __syncthreads();
  }
  if (t == 0) atomicAdd(sse, red[0]);
}

// ---------------- final losses ----------------
__global__ void k_final(const float* __restrict__ acc, float* __restrict__ out) {
  if (threadIdx.x == 0 && blockIdx.x == 0) {
    float vq = acc[0] / 4194304.f;   // mean over 256*256*8*8
    float rec = acc[1] / 786432.f;   // mean over 256*3*32*32
    out[0] = rec + 2.f * vq;         // total = rec + dict + beta*commit
    out[1] = rec;
    out[2] = vq;
    out[3] = vq;
  }
}

extern "C" void kernel_launch(void* const* d_in, const int* in_sizes, int n_in,
                              void* d_out, int out_size, void* d_ws, size_t ws_size,
                              hipStream_t stream) {
  (void)in_sizes; (void)n_in; (void)out_size; (void)ws_size;
  const float* x = (const float*)d_in[0];
  const float* ew1 = (const float*)d_in[1];
  const float* eb1 = (const float*)d_in[2];
  const float* ew2 = (const float*)d_in[3];
  const float* eb2 = (const float*)d_in[4];
  const float* rmsw = (const float*)d_in[5];
  const float* r3w = (const float*)d_in[6];
  const float* r3b = (const float*)d_in[7];
  const float* r1w = (const float*)d_in[8];
  const float* r1b = (const float*)d_in[9];
  const float* emb = (const float*)d_in[10];
  const float* dw1 = (const float*)d_in[11];
  const float* db1 = (const float*)d_in[12];
  const float* dw2 = (const float*)d_in[13];
  const float* db2 = (const float*)d_in[14];
  float* out = (float*)d_out;

  float* wsf = (float*)d_ws;
  float* P = wsf + OFF_P;
  float* Q = wsf + OFF_Q;
  float* H1 = wsf + OFF_H1;
  float* wT2 = wsf + OFF_WT2;
  float* wT3 = wsf + OFF_WT3;
  float* wT1 = wsf + OFF_WT1;
  float* wTd1 = wsf + OFF_WTD1;
  float* wTd2 = wsf + OFF_WTD2;
  float* embT = wsf + OFF_EMBT;
  float* enorm = wsf + OFF_ENORM;
  float* rs = wsf + OFF_RS;
  float* acc = wsf + OFF_ACC;

  k_zero2<<<1, 64, 0, stream>>>(acc);

  // weight prep
  k_transpose<<<4096, 256, 0, stream>>>(ew2, wT2, 256, 4096, 1048576);
  k_transpose<<<9216, 256, 0, stream>>>(r3w, wT3, 256, 2304, 2359296);
  k_transpose<<<1024, 256, 0, stream>>>(r1w, wT1, 256, 256, 262144);
  k_transpose<<<512, 256, 0, stream>>>(emb, embT, 512, 256, 131072);
  k_transpose_dec1<<<4096, 256, 0, stream>>>(dw1, wTd1);
  k_prep_dec2<<<48, 256, 0, stream>>>(dw2, wTd2);
  k_enorm<<<8, 64, 0, stream>>>(emb, enorm);

  // encoder
  k_conv1<<<65536, 256, 0, stream>>>(x, ew1, eb1, H1);
  k_conv2<<<16384, 256, 0, stream>>>(H1, wT2, eb2, P);
  for (int rb = 0; rb < 2; ++rb) {
    k_rms<<<256, 256, 0, stream>>>(P, rs);
    k_res3<<<16384, 256, 0, stream>>>(P, rs, rmsw + (size_t)(rb * 2 + 0) * 16384,
                                      wT3 + (size_t)rb * 589824, r3b + rb * 256, Q);
    k_rms<<<256, 256, 0, stream>>>(Q, rs);
    k_res1<<<16384, 256, 0, stream>>>(Q, rs, rmsw + (size_t)(rb * 2 + 1) * 16384,
                                      wT1 + (size_t)rb * 65536, r1b + rb * 256, P);
  }

  // VQ: P -> Q (q values), sse_vq into acc[0]
  k_vq<<<16384, 256, 0, stream>>>(P, embT, emb, enorm, Q, acc + 0);

  // decoder res blocks
  for (int rb = 2; rb < 4; ++rb) {
    k_rms<<<256, 256, 0, stream>>>(Q, rs);
    k_res3<<<16384, 256, 0, stream>>>(Q, rs, rmsw + (size_t)(rb * 2 + 0) * 16384,
                                      wT3 + (size_t)rb * 589824, r3b + rb * 256, P);
    k_rms<<<256, 256, 0, stream>>>(P, rs);
    k_res1<<<16384, 256, 0, stream>>>(P, rs, rmsw + (size_t)(rb * 2 + 1) * 16384,
                                      wT1 + (size_t)rb * 65536, r1b + rb * 256, Q);
  }

  k_deconv1<<<65536, 256, 0, stream>>>(Q, wTd1, db1, H1);
  k_deconv2<<<8192, 256, 0, stream>>>(H1, wTd2, db2, x, out + 4, acc + 1);
  k_final<<<1, 64, 0, stream>>>(acc, out);
}

// Round 4
// 1602.686 us; speedup vs baseline: 7.0355x; 7.0355x over previous
//
#include <hip/hip_runtime.h>
#include <hip/hip_bf16.h>

typedef unsigned short ushort_t;
typedef __attribute__((ext_vector_type(8))) short short8v;
typedef __attribute__((ext_vector_type(4))) float f32x4;

__device__ __forceinline__ ushort_t f2bs(float v) {
  union { __hip_bfloat16 h; ushort_t u; } cv;
  cv.h = __float2bfloat16(v);
  return cv.u;
}
__device__ __forceinline__ float bs2f(ushort_t u) {
  union { ushort_t u; __hip_bfloat16 h; } cv;
  cv.u = u;
  return __bfloat162float(cv.h);
}

// async global->LDS, 16B/lane; lds dest = wave-uniform base + lane*16
__device__ __forceinline__ void glds16(const ushort_t* g, ushort_t* l) {
  __builtin_amdgcn_global_load_lds(
      (const __attribute__((address_space(1))) unsigned int*)(uintptr_t)g,
      (__attribute__((address_space(3))) unsigned int*)(unsigned int)(uintptr_t)l,
      16, 0, 0);
}

// ---------------- workspace layout (total ~109.6 MB; round-2 proved >=114.5 MB ok) ----
// fp32 region (float offsets):
static constexpr size_t OFF_P = 0;           // 16384x256 residual stream (fp32)
static constexpr size_t OFF_ENORM = 4194304; // 512
static constexpr size_t OFF_WTD2 = 4194816;  // 12288 dec_w2 [ic][tap][oc3]
static constexpr size_t OFF_RS = 4207104;    // 256 per-sample rsqrt
static constexpr size_t OFF_ACC = 4207360;   // 8: [0]=sse_vq [1]=sse_rec
static constexpr size_t OFF_ZROW = 4207368;  // 64 zero floats (OOB page)
static constexpr size_t OFF_SHORT = 4207432; // ushort region start (16B aligned)
// ushort offsets (from sb):
static constexpr size_t SO_H1H = 0;         // 65536x256 conv1-out hi; later deconv1 out (H2B)
static constexpr size_t SO_H1L = 16777216;  // 65536x256 conv1-out lo; later Qf fp32 (4194304 fl)
static constexpr size_t SO_NBH = 33554432;  // 16384x256 norm hi; earlier A1h 65536x64
static constexpr size_t SO_NBL = 37748736;  // 16384x256 norm lo; earlier A1l; later QB
static constexpr size_t SO_W1H = 41943040;  // conv1 W hi [256][64]
static constexpr size_t SO_W1L = 41959424;
static constexpr size_t SO_W2H = 41975808;  // conv2 W hi [256][4096]
static constexpr size_t SO_W2L = 43024384;
static constexpr size_t SO_W3EH = 44072960; // enc res3 W hi [2][256][2304]
static constexpr size_t SO_W3EL = 45252608;
static constexpr size_t SO_W3D = 46432256;  // dec res3 W [2][256][2304]
static constexpr size_t SO_W1REH = 47611904; // enc res1 W hi [2][256][256]
static constexpr size_t SO_W1REL = 47742976;
static constexpr size_t SO_W1RD = 47874048;  // dec res1 W [2][256][256]
static constexpr size_t SO_WD1 = 48005120;   // deconv1 W [4cls][256][1024]

// ---------------- prep ----------------
__global__ void k_zero(float* __restrict__ acc, float* __restrict__ zrow) {
  if (blockIdx.x == 0) {
    if (threadIdx.x < 2) acc[threadIdx.x] = 0.f;
    if (threadIdx.x < 64) zrow[threadIdx.x] = 0.f;
  }
}

__device__ __forceinline__ void split_store(float v, ushort_t* hi, ushort_t* lo, size_t i) {
  ushort_t h = f2bs(v);
  hi[i] = h;
  lo[i] = f2bs(v - bs2f(h));
}

__global__ void k_w1(const float* __restrict__ src, ushort_t* __restrict__ h,
                     ushort_t* __restrict__ l) {
  int i = blockIdx.x * 256 + threadIdx.x;
  if (i >= 16384) return;
  int oc = i >> 6, k = i & 63;
  float v = 0.f;
  if (k < 48) {
    int tap = k / 3, ic = k - 3 * tap;
    v = src[(oc * 3 + ic) * 16 + tap];
  }
  split_store(v, h, l, i);
}

__global__ void k_w2(const float* __restrict__ src, ushort_t* __restrict__ h,
                     ushort_t* __restrict__ l) {
  int i = blockIdx.x * 256 + threadIdx.x;  // 1048576
  int oc = i >> 12, k = i & 4095;
  int tap = k >> 8, ic = k & 255;
  split_store(src[(oc * 256 + ic) * 16 + tap], h, l, i);
}

__global__ void k_w3e(const float* __restrict__ src, ushort_t* __restrict__ h,
                      ushort_t* __restrict__ l) {
  int i = blockIdx.x * 256 + threadIdx.x;  // 1179648
  int rb = i / 589824, r2 = i - rb * 589824;
  int oc = r2 / 2304, k = r2 - oc * 2304;
  int r9 = k >> 8, ic = k & 255;
  split_store(src[((rb * 256 + oc) * 256 + ic) * 9 + r9], h, l, i);
}

__global__ void k_w3d(const float* __restrict__ src, ushort_t* __restrict__ h) {
  int i = blockIdx.x * 256 + threadIdx.x;  // 1179648
  int rb = i / 589824, r2 = i - rb * 589824;
  int oc = r2 / 2304, k = r2 - oc * 2304;
  int r9 = k >> 8, ic = k & 255;
  h[i] = f2bs(src[((rb * 256 + oc) * 256 + ic) * 9 + r9]);
}

__global__ void k_w1re(const float* __restrict__ src, ushort_t* __restrict__ h,
                       ushort_t* __restrict__ l) {
  int i = blockIdx.x * 256 + threadIdx.x;  // 131072 (layout already [rb][oc][ic])
  split_store(src[i], h, l, i);
}

__global__ void k_w1rd(const float* __restrict__ src, ushort_t* __restrict__ h) {
  int i = blockIdx.x * 256 + threadIdx.x;  // 131072
  h[i] = f2bs(src[i]);
}

__global__ void k_wd1(const float* __restrict__ src, ushort_t* __restrict__ dst) {
  int i = blockIdx.x * 256 + threadIdx.x;  // 1048576
  int cls = i >> 18, r2 = i & 262143;
  int oc = r2 >> 10, k = r2 & 1023;
  int tap = k >> 8, ic = k & 255;
  int s = tap >> 1, sx = tap & 1;
  int py = cls >> 1, px = cls & 1;
  int ky = py + 2 - 2 * s, kx = px + 2 - 2 * sx;
  dst[i] = f2bs(src[(ic * 256 + oc) * 16 + ky * 4 + kx]);
}

__global__ void k_prep_dec2(const float* __restrict__ src, float* __restrict__ dst) {
  int i = blockIdx.x * 256 + threadIdx.x;
  if (i >= 12288) return;
  int kyx = i & 15;
  int r = i >> 4;
  int oc = r % 3;
  int ic = r / 3;
  dst[(ic * 16 + kyx) * 3 + oc] = src[i];
}

__global__ void k_enorm(const float* __restrict__ emb, float* __restrict__ enorm) {
  int e = blockIdx.x * 64 + threadIdx.x;
  if (e >= 512) return;
  float s = 0.f;
  for (int c = 0; c < 256; ++c) {
    float v = emb[e * 256 + c];
    s += v * v;
  }
  enorm[e] = s;
}

__global__ void k_build_a1(const float* __restrict__ x, ushort_t* __restrict__ h,
                           ushort_t* __restrict__ l) {
  int i = blockIdx.x * 256 + threadIdx.x;  // 4194304
  int t1 = i >> 6, k = i & 63;
  float v = 0.f;
  if (k < 48) {
    int tap = k / 3, ic = k - 3 * tap;
    int n = t1 >> 8, oy = (t1 >> 4) & 15, ox = t1 & 15;
    int ky = tap >> 2, kx = tap & 3;
    int iy = 2 * oy - 1 + ky, ix = 2 * ox - 1 + kx;
    if ((unsigned)iy < 32u && (unsigned)ix < 32u)
      v = x[((n * 3 + ic) * 32 + iy) * 32 + ix];
  }
  split_store(v, h, l, i);
}

// ---------------- MFMA GEMM (BM=128,BN=64,BK=32; implicit im2col; optional split) ---
// SPLIT: K-loop runs 3K as [Ah|Al|Ah] x [Bh|Bh|Bl] -> AhBh+AlBh+AhBl (fp32-grade)
// MODE: 0=direct A (stride K), 1=conv2 im2col (16x16 grid, stride 256),
//       2=res3 3x3 im2col (8x8 grid), 3=deconv1 tap (8x8 grid, cls=blockIdx.z)
// EPI:  1=relu->f32, 2=res+relu->f32, 3=deconv1 remap relu->bf16, 4=relu->split bf16
template <int MODE, int EPI, int SPLIT>
__global__ __launch_bounds__(256) void k_gemm(const ushort_t* __restrict__ Ah,
                                              const ushort_t* __restrict__ Al,
                                              const ushort_t* __restrict__ Bh,
                                              const ushort_t* __restrict__ Bl, int K,
                                              const float* __restrict__ bias,
                                              const float* __restrict__ res,
                                              float* __restrict__ outf,
                                              ushort_t* __restrict__ outb,
                                              ushort_t* __restrict__ outb2,
                                              const ushort_t* __restrict__ zrow) {
  __shared__ __align__(16) ushort_t As[128 * 32];
  __shared__ __align__(16) ushort_t Bs[64 * 32];
  const int t = threadIdx.x;
  const int w = t >> 6, l = t & 63;
  const int M0 = blockIdx.x * 128, N0 = blockIdx.y * 64;
  int py = 0, px = 0;
  const ushort_t* Bh2 = Bh;
  if (MODE == 3) {
    int cls = blockIdx.z;
    py = cls >> 1;
    px = cls & 1;
    Bh2 = Bh + (size_t)cls * 262144;
  }
  const int srow = l >> 2, chunk = l & 3;
  const int ar1 = w * 32 + srow, ar2 = ar1 + 16;
  const int br = w * 16 + srow;
  const int tok1 = M0 + ar1, tok2 = M0 + ar2;
  const int fr = l & 15, kg = (l >> 4) * 8;
  const int m_off = (w & 1) * 64, n_off = (w >> 1) * 32;

  f32x4 acc[4][2];
#pragma unroll
  for (int i = 0; i < 4; ++i)
#pragma unroll
    for (int j = 0; j < 2; ++j) acc[i][j] = (f32x4){0.f, 0.f, 0.f, 0.f};

  ushort_t* adst1 = As + w * 1024;
  ushort_t* adst2 = adst1 + 512;
  ushort_t* bdst = Bs + w * 512;

  int n1 = tok1 >> 6, oy1 = (tok1 >> 3) & 7, ox1 = tok1 & 7;
  int n2 = tok2 >> 6, oy2 = (tok2 >> 3) & 7, ox2 = tok2 & 7;

  const int KT = SPLIT ? 3 * K : K;
  for (int k0 = 0; k0 < KT; k0 += 32) {
    int third = 0, kk = k0;
    if (SPLIT) {
      third = (k0 >= 2 * K) ? 2 : (int)(k0 >= K);
      kk = k0 - third * K;
    }
    const ushort_t* Ab = (SPLIT && third == 1) ? Al : Ah;
    const ushort_t* Bb = (SPLIT && third == 2) ? Bl : Bh2;
    const ushort_t* bsrc = Bb + (size_t)(N0 + br) * K + kk + chunk * 8;
    const ushort_t* a1;
    const ushort_t* a2;
    if (MODE == 0) {
      a1 = Ab + (size_t)tok1 * K + kk + chunk * 8;
      a2 = Ab + (size_t)tok2 * K + kk + chunk * 8;
    } else if (MODE == 1) {
      int tap = kk >> 8, kin = (kk & 255) + chunk * 8;
      int ky = tap >> 2, kx = tap & 3;
      int iy1 = 2 * oy1 - 1 + ky, ix1 = 2 * ox1 - 1 + kx;
      int iy2 = 2 * oy2 - 1 + ky, ix2 = 2 * ox2 - 1 + kx;
      a1 = ((unsigned)iy1 < 16u && (unsigned)ix1 < 16u)
               ? Ab + (size_t)(((n1 << 8) + (iy1 << 4) + ix1) << 8) + kin
               : zrow + chunk * 8;
      a2 = ((unsigned)iy2 < 16u && (unsigned)ix2 < 16u)
               ? Ab + (size_t)(((n2 << 8) + (iy2 << 4) + ix2) << 8) + kin
               : zrow + chunk * 8;
    } else if (MODE == 2) {
      int r9 = kk >> 8, kin = (kk & 255) + chunk * 8;
      int ky = r9 / 3, kx = r9 - ky * 3;
      int iy1 = oy1 - 1 + ky, ix1 = ox1 - 1 + kx;
      int iy2 = oy2 - 1 + ky, ix2 = ox2 - 1 + kx;
      a1 = ((unsigned)iy1 < 8u && (unsigned)ix1 < 8u)
               ? Ab + (size_t)(((n1 << 6) + (iy1 << 3) + ix1) << 8) + kin
               : zrow + chunk * 8;
      a2 = ((unsigned)iy2 < 8u && (unsigned)ix2 < 8u)
               ? Ab + (size_t)(((n2 << 6) + (iy2 << 3) + ix2) << 8) + kin
               : zrow + chunk * 8;
    } else {
      int tap = kk >> 8, kin = (kk & 255) + chunk * 8;
      int s = tap >> 1, sx = tap & 1;
      int iy1 = oy1 + s - py, ix1 = ox1 + sx - px;
      int iy2 = oy2 + s - py, ix2 = ox2 + sx - px;
      a1 = ((unsigned)iy1 < 8u && (unsigned)ix1 < 8u)
               ? Ab + (size_t)(((n1 << 6) + (iy1 << 3) + ix1) << 8) + kin
               : zrow + chunk * 8;
      a2 = ((unsigned)iy2 < 8u && (unsigned)ix2 < 8u)
               ? Ab + (size_t)(((n2 << 6) + (iy2 << 3) + ix2) << 8) + kin
               : zrow + chunk * 8;
    }
    glds16(a1, adst1);
    glds16(a2, adst2);
    glds16(bsrc, bdst);
    __syncthreads();
    short8v af[4];
    short8v bf[2];
#pragma unroll
    for (int mi = 0; mi < 4; ++mi)
      af[mi] = *(const short8v*)(As + (m_off + mi * 16 + fr) * 32 + kg);
#pragma unroll
    for (int nj = 0; nj < 2; ++nj)
      bf[nj] = *(const short8v*)(Bs + (n_off + nj * 16 + fr) * 32 + kg);
#pragma unroll
    for (int mi = 0; mi < 4; ++mi)
#pragma unroll
      for (int nj = 0; nj < 2; ++nj)
        acc[mi][nj] =
            __builtin_amdgcn_mfma_f32_16x16x32_bf16(af[mi], bf[nj], acc[mi][nj], 0, 0, 0);
    __syncthreads();
  }

#pragma unroll
  for (int mi = 0; mi < 4; ++mi) {
    int mrow = m_off + mi * 16 + (l >> 4) * 4;
#pragma unroll
    for (int nj = 0; nj < 2; ++nj) {
      int col = N0 + n_off + nj * 16 + fr;
      float bv = bias[col];
#pragma unroll
      for (int i = 0; i < 4; ++i) {
        int m = M0 + mrow + i;
        float v = fmaxf(acc[mi][nj][i] + bv, 0.f);
        if (EPI == 1) {
          outf[(size_t)m * 256 + col] = v;
        } else if (EPI == 2) {
          size_t o = (size_t)m * 256 + col;
          outf[o] = res[o] + v;
        } else if (EPI == 3) {
          int nn = m >> 6, jj = (m >> 3) & 7, ii = m & 7;
          int oy = 2 * jj + 1 - py, ox = 2 * ii + 1 - px;
          outb[(size_t)((nn << 8) + oy * 16 + ox) * 256 + col] = f2bs(v);
        } else {  // EPI 4: split bf16
          size_t o = (size_t)m * 256 + col;
          ushort_t h = f2bs(v);
          outb[o] = h;
          outb2[o] = f2bs(v - bs2f(h));
        }
      }
    }
  }
}

// ---------------- per-sample rms ----------------
__global__ void __launch_bounds__(256) k_rms(const float* __restrict__ x, float* __restrict__ rs) {
  __shared__ float sd[256];
  int n = blockIdx.x, t = threadIdx.x;
  const float* p = x + (size_t)n * 16384;
  float s = 0.f;
  for (int i = t; i < 16384; i += 256) {
    float v = p[i];
    s += v * v;
  }
  sd[t] = s;
  __syncthreads();
  for (int k = 128; k > 0; k >>= 1) {
    if (t < k) sd[t] += sd[t + k];
    __syncthreads();
  }
  if (t == 0) rs[n] = 1.0f / sqrtf(sd[0] / 16384.f + 1.1920929e-07f);
}

// normalized activations; rmsw original layout [slice][c][yx]
template <int SPLIT>
__global__ void __launch_bounds__(256) k_norm(const float* __restrict__ in,
                                              const float* __restrict__ rs,
                                              const float* __restrict__ rmsw,
                                              ushort_t* __restrict__ NBh,
                                              ushort_t* __restrict__ NBl) {
  int tk = blockIdx.x, c = threadIdx.x;
  float v = in[(size_t)tk * 256 + c] * rs[tk >> 6] * rmsw[c * 64 + (tk & 63)];
  size_t o = (size_t)tk * 256 + c;
  ushort_t h = f2bs(v);
  NBh[o] = h;
  if (SPLIT) NBl[o] = f2bs(v - bs2f(h));
}

__global__ void __launch_bounds__(256) k_cast(const float* __restrict__ in,
                                              ushort_t* __restrict__ out) {
  int i = blockIdx.x * 256 + threadIdx.x;
  out[i] = f2bs(in[i]);
}

// ---------------- VQ: 16 tokens/block, fp32, emb read directly ----------------
__global__ void __launch_bounds__(256) k_vq(const float* __restrict__ enc,
                                            const float* __restrict__ emb,
                                            const float* __restrict__ enorm,
                                            float* __restrict__ q, float* __restrict__ sse) {
  __shared__ float z[16][256];
  __shared__ float sc[512 * 16];
  __shared__ float bv[16][16];
  __shared__ int bi[16][16];
  __shared__ int idxs[16];
  int T0 = blockIdx.x * 16;
  int t = threadIdx.x;
  for (int j = 0; j < 16; ++j) z[j][t] = enc[(size_t)(T0 + j) * 256 + t];
  __syncthreads();
  float d0[16], d1[16];
#pragma unroll
  for (int j = 0; j < 16; ++j) { d0[j] = 0.f; d1[j] = 0.f; }
  const float4* e0 = (const float4*)(emb + (size_t)t * 256);
  const float4* e1 = (const float4*)(emb + (size_t)(t + 256) * 256);
  for (int c4 = 0; c4 < 64; ++c4) {
    float4 ea = e0[c4];
    float4 eb = e1[c4];
#pragma unroll
    for (int j = 0; j < 16; ++j) {
      float4 zv = *(const float4*)&z[j][c4 * 4];
      d0[j] += zv.x * ea.x + zv.y * ea.y + zv.z * ea.z + zv.w * ea.w;
      d1[j] += zv.x * eb.x + zv.y * eb.y + zv.z * eb.z + zv.w * eb.w;
    }
  }
  float en0 = enorm[t], en1 = enorm[t + 256];
#pragma unroll
  for (int j = 0; j < 16; ++j) {
    sc[t * 16 + j] = en0 - 2.f * d0[j];
    sc[(t + 256) * 16 + j] = en1 - 2.f * d1[j];
  }
  __syncthreads();
  {
    int j = t & 15, chunk = t >> 4;
    float best = 3.4e38f;
    int bidx = 0;
    int c0 = chunk * 32;
    for (int cc = 0; cc < 32; ++cc) {
      float v = sc[(c0 + cc) * 16 + j];
      if (v < best) { best = v; bidx = c0 + cc; }
    }
    bv[chunk][j] = best;
    bi[chunk][j] = bidx;
  }
  __syncthreads();
  if (t < 16) {
    float best = 3.4e38f;
    int bidx = 0;
    for (int c = 0; c < 16; ++c) {
      float v = bv[c][t];
      if (v < best) { best = v; bidx = bi[c][t]; }
    }
    idxs[t] = bidx;
  }
  __syncthreads();
  float sq = 0.f;
  for (int j = 0; j < 16; ++j) {
    float e = emb[(size_t)idxs[j] * 256 + t];
    q[(size_t)(T0 + j) * 256 + t] = e;
    float d = z[j][t] - e;
    sq += d * d;
  }
  __syncthreads();
  sc[t] = sq;
  __syncthreads();
  for (int k = 128; k > 0; k >>= 1) {
    if (t < k) sc[t] += sc[t + k];
    __syncthreads();
  }
  if (t == 0) atomicAdd(sse, sc[0]);
}

// ---------------- deconv2 + reconst loss ----------------
__global__ void __launch_bounds__(256) k_deconv2(const ushort_t* __restrict__ in,
                                                 const float* __restrict__ wT,
                                                 const float* __restrict__ bias,
                                                 const float* __restrict__ x,
                                                 float* __restrict__ dec,
                                                 float* __restrict__ sse) {
  __shared__ float patch[9216];  // [ic=256][s=2][col=18]
  __shared__ float red[768];
  int blk = blockIdx.x;  // 8192 = n*32 + oy
  int oy = blk & 31, n = blk >> 5;
  int t = threadIdx.x;
  int py = (oy + 1) & 1;
  int dy = (oy + 1 - py) >> 1;
  for (int it = 0; it < 36; ++it) {
    int s = it / 18, col = it - s * 18;
    int ix = col - 1, iy = dy - 1 + s;
    float v = 0.f;
    if ((unsigned)iy < 16u && (unsigned)ix < 16u)
      v = bs2f(in[(size_t)((n << 8) + iy * 16 + ix) * 256 + t]);
    patch[(t * 2 + s) * 18 + col] = v;
  }
  __syncthreads();
  int ox = t & 31, g = t >> 5;
  int px = (ox + 1) & 1;
  int dx = (ox + 1 - px) >> 1;
  int k00 = ((py + 2) * 4 + px + 2) * 3;
  int k01 = k00 - 6;
  int k10 = (py * 4 + px + 2) * 3;
  int k11 = k10 - 6;
  float a0 = 0.f, a1 = 0.f, a2 = 0.f;
  for (int ic = g * 32; ic < g * 32 + 32; ++ic) {
    const float* pp = patch + ic * 36;
    float v00 = pp[dx], v01 = pp[dx + 1], v10 = pp[18 + dx], v11 = pp[18 + dx + 1];
    const float* ww = wT + ic * 48;
    a0 += v00 * ww[k00 + 0] + v01 * ww[k01 + 0] + v10 * ww[k10 + 0] + v11 * ww[k11 + 0];
    a1 += v00 * ww[k00 + 1] + v01 * ww[k01 + 1] + v10 * ww[k10 + 1] + v11 * ww[k11 + 1];
    a2 += v00 * ww[k00 + 2] + v01 * ww[k01 + 2] + v10 * ww[k10 + 2] + v11 * ww[k11 + 2];
  }
  red[t * 3 + 0] = a0;
  red[t * 3 + 1] = a1;
  red[t * 3 + 2] = a2;
  __syncthreads();
  float sq = 0.f;
  if (t < 96) {
    int ox2 = t & 31, oc = t >> 5;
    float v = bias[oc];
#pragma unroll
    for (int g2 = 0; g2 < 8; ++g2) v += red[(g2 * 32 + ox2) * 3 + oc];
    int oi = ((n * 3 + oc) * 32 + oy) * 32 + ox2;
    dec[oi] = v;
    float d = v - x[oi];
    sq = d * d;
  }
  __syncthreads();
  red[t] = sq;
  __syncthreads();
  for (int k = 128; k > 0; k >>= 1) {
    if (t < k) red[t] += red[t + k];
    __syncthreads();
  }
  if (t == 0) atomicAdd(sse, red[0]);
}

__global__ void k_final(const float* __restrict__ acc, float* __restrict__ out) {
  if (threadIdx.x == 0 && blockIdx.x == 0) {
    float vq = acc[0] / 4194304.f;
    float rec = acc[1] / 786432.f;
    out[0] = rec + 2.f * vq;
    out[1] = rec;
    out[2] = vq;
    out[3] = vq;
  }
}

extern "C" void kernel_launch(void* const* d_in, const int* in_sizes, int n_in,
                              void* d_out, int out_size, void* d_ws, size_t ws_size,
                              hipStream_t stream) {
  (void)in_sizes; (void)n_in; (void)out_size; (void)ws_size;
  const float* x = (const float*)d_in[0];
  const float* ew1 = (const float*)d_in[1];
  const float* eb1 = (const float*)d_in[2];
  const float* ew2 = (const float*)d_in[3];
  const float* eb2 = (const float*)d_in[4];
  const float* rmsw = (const float*)d_in[5];
  const float* r3w = (const float*)d_in[6];
  const float* r3b = (const float*)d_in[7];
  const float* r1w = (const float*)d_in[8];
  const float* r1b = (const float*)d_in[9];
  const float* emb = (const float*)d_in[10];
  const float* dw1 = (const float*)d_in[11];
  const float* db1 = (const float*)d_in[12];
  const float* dw2 = (const float*)d_in[13];
  const float* db2 = (const float*)d_in[14];
  float* out = (float*)d_out;

  float* wsf = (float*)d_ws;
  float* P = wsf + OFF_P;
  float* enorm = wsf + OFF_ENORM;
  float* wTd2 = wsf + OFF_WTD2;
  float* rs = wsf + OFF_RS;
  float* acc = wsf + OFF_ACC;
  float* zrowf = wsf + OFF_ZROW;
  ushort_t* sb = (ushort_t*)(wsf + OFF_SHORT);
  ushort_t* H1H = sb + SO_H1H;   // conv1 hi; later H2B (deconv1 out)
  ushort_t* H1L = sb + SO_H1L;   // conv1 lo; later Qf
  float* Qf = (float*)(sb + SO_H1L);
  ushort_t* NBH = sb + SO_NBH;   // also A1h
  ushort_t* NBL = sb + SO_NBL;   // also A1l, QB
  ushort_t* A1H = NBH;
  ushort_t* A1L = NBL;
  ushort_t* QB = NBL;
  ushort_t* W1H = sb + SO_W1H;
  ushort_t* W1L = sb + SO_W1L;
  ushort_t* W2H = sb + SO_W2H;
  ushort_t* W2L = sb + SO_W2L;
  ushort_t* W3EH = sb + SO_W3EH;
  ushort_t* W3EL = sb + SO_W3EL;
  ushort_t* W3D = sb + SO_W3D;
  ushort_t* W1REH = sb + SO_W1REH;
  ushort_t* W1REL = sb + SO_W1REL;
  ushort_t* W1RD = sb + SO_W1RD;
  ushort_t* WD1 = sb + SO_WD1;
  const ushort_t* zrow = (const ushort_t*)zrowf;

  k_zero<<<1, 256, 0, stream>>>(acc, zrowf);

  // weight prep
  k_w1<<<64, 256, 0, stream>>>(ew1, W1H, W1L);
  k_w2<<<4096, 256, 0, stream>>>(ew2, W2H, W2L);
  k_w3e<<<4608, 256, 0, stream>>>(r3w, W3EH, W3EL);
  k_w3d<<<4608, 256, 0, stream>>>(r3w + 2 * 589824, W3D);
  k_w1re<<<512, 256, 0, stream>>>(r1w, W1REH, W1REL);
  k_w1rd<<<512, 256, 0, stream>>>(r1w + 2 * 65536, W1RD);
  k_wd1<<<4096, 256, 0, stream>>>(dw1, WD1);
  k_prep_dec2<<<48, 256, 0, stream>>>(dw2, wTd2);
  k_enorm<<<8, 64, 0, stream>>>(emb, enorm);

  // encoder (split-bf16, fp32-grade)
  k_build_a1<<<16384, 256, 0, stream>>>(x, A1H, A1L);
  k_gemm<0, 4, 1><<<dim3(512, 4), 256, 0, stream>>>(A1H, A1L, W1H, W1L, 64, eb1,
                                                    nullptr, nullptr, H1H, H1L, zrow);
  k_gemm<1, 1, 1><<<dim3(128, 4), 256, 0, stream>>>(H1H, H1L, W2H, W2L, 4096, eb2,
                                                    nullptr, P, nullptr, nullptr, zrow);
  for (int rb = 0; rb < 2; ++rb) {
    k_rms<<<256, 256, 0, stream>>>(P, rs);
    k_norm<1><<<16384, 256, 0, stream>>>(P, rs, rmsw + (size_t)(rb * 2 + 0) * 16384, NBH, NBL);
    k_gemm<2, 2, 1><<<dim3(128, 4), 256, 0, stream>>>(
        NBH, NBL, W3EH + (size_t)rb * 589824, W3EL + (size_t)rb * 589824, 2304,
        r3b + rb * 256, P, Qf, nullptr, nullptr, zrow);
    k_rms<<<256, 256, 0, stream>>>(Qf, rs);
    k_norm<1><<<16384, 256, 0, stream>>>(Qf, rs, rmsw + (size_t)(rb * 2 + 1) * 16384, NBH, NBL);
    k_gemm<0, 2, 1><<<dim3(128, 4), 256, 0, stream>>>(
        NBH, NBL, W1REH + (size_t)rb * 65536, W1REL + (size_t)rb * 65536, 256,
        r1b + rb * 256, Qf, P, nullptr, nullptr, zrow);
  }

  // VQ: P (enc) -> Qf (q), sse -> acc[0]
  k_vq<<<1024, 256, 0, stream>>>(P, emb, enorm, Qf, acc + 0);

  // decoder res blocks (plain bf16)
  for (int rb = 2; rb < 4; ++rb) {
    k_rms<<<256, 256, 0, stream>>>(Qf, rs);
    k_norm<0><<<16384, 256, 0, stream>>>(Qf, rs, rmsw + (size_t)(rb * 2 + 0) * 16384, NBH, nullptr);
    k_gemm<2, 2, 0><<<dim3(128, 4), 256, 0, stream>>>(
        NBH, nullptr, W3D + (size_t)(rb - 2) * 589824, nullptr, 2304,
        r3b + rb * 256, Qf, P, nullptr, nullptr, zrow);
    k_rms<<<256, 256, 0, stream>>>(P, rs);
    k_norm<0><<<16384, 256, 0, stream>>>(P, rs, rmsw + (size_t)(rb * 2 + 1) * 16384, NBH, nullptr);
    k_gemm<0, 2, 0><<<dim3(128, 4), 256, 0, stream>>>(
        NBH, nullptr, W1RD + (size_t)(rb - 2) * 65536, nullptr, 256,
        r1b + rb * 256, P, Qf, nullptr, nullptr, zrow);
  }

  // deconv1 (4 parity classes) -> H2B (= H1H region)
  k_cast<<<16384, 256, 0, stream>>>(Qf, QB);
  k_gemm<3, 3, 0><<<dim3(128, 4, 4), 256, 0, stream>>>(QB, nullptr, WD1, nullptr, 1024, db1,
                                                       nullptr, nullptr, H1H, nullptr, zrow);

  // deconv2 + reconst loss
  k_deconv2<<<8192, 256, 0, stream>>>(H1H, wTd2, db2, x, out + 4, acc + 1);
  k_final<<<1, 64, 0, stream>>>(acc, out);
}

// Round 5
// 1355.278 us; speedup vs baseline: 8.3198x; 1.1826x over previous
//
#include <hip/hip_runtime.h>
#include <hip/hip_bf16.h>

typedef unsigned short ushort_t;
typedef __attribute__((ext_vector_type(8))) short short8v;
typedef __attribute__((ext_vector_type(4))) float f32x4;

__device__ __forceinline__ ushort_t f2bs(float v) {
  union { __hip_bfloat16 h; ushort_t u; } cv;
  cv.h = __float2bfloat16(v);
  return cv.u;
}
__device__ __forceinline__ float bs2f(ushort_t u) {
  union { ushort_t u; __hip_bfloat16 h; } cv;
  cv.u = u;
  return __bfloat162float(cv.h);
}

// async global->LDS, 16B/lane; lds dest = wave-uniform base + lane*16
__device__ __forceinline__ void glds16(const ushort_t* g, ushort_t* l) {
  __builtin_amdgcn_global_load_lds(
      (const __attribute__((address_space(1))) unsigned int*)(uintptr_t)g,
      (__attribute__((address_space(3))) unsigned int*)(unsigned int)(uintptr_t)l,
      16, 0, 0);
}

// ---------------- workspace layout (unchanged from round 4) ----------------
static constexpr size_t OFF_P = 0;           // 16384x256 residual stream (fp32)
static constexpr size_t OFF_ENORM = 4194304; // 512
static constexpr size_t OFF_WTD2 = 4194816;  // 12288 dec_w2 [ic][tap][oc3]
static constexpr size_t OFF_RS = 4207104;    // 256 (unused now, kept for layout)
static constexpr size_t OFF_ACC = 4207360;   // 8: [0]=sse_vq [1]=sse_rec
static constexpr size_t OFF_ZROW = 4207368;  // 64 zero floats (OOB page)
static constexpr size_t OFF_SHORT = 4207432; // ushort region start (16B aligned)
static constexpr size_t SO_H1H = 0;         // 65536x256 conv1-out hi; later deconv1 out
static constexpr size_t SO_H1L = 16777216;  // 65536x256 conv1-out lo; later Qf fp32
static constexpr size_t SO_NBH = 33554432;  // 16384x256 norm hi; earlier A1h
static constexpr size_t SO_NBL = 37748736;  // 16384x256 norm lo; earlier A1l; later QB
static constexpr size_t SO_W1H = 41943040;
static constexpr size_t SO_W1L = 41959424;
static constexpr size_t SO_W2H = 41975808;
static constexpr size_t SO_W2L = 43024384;
static constexpr size_t SO_W3EH = 44072960;
static constexpr size_t SO_W3EL = 45252608;
static constexpr size_t SO_W3D = 46432256;
static constexpr size_t SO_W1REH = 47611904;
static constexpr size_t SO_W1REL = 47742976;
static constexpr size_t SO_W1RD = 47874048;
static constexpr size_t SO_WD1 = 48005120;

// ---------------- prep ----------------
__global__ void k_zero(float* __restrict__ acc, float* __restrict__ zrow) {
  if (blockIdx.x == 0) {
    if (threadIdx.x < 2) acc[threadIdx.x] = 0.f;
    if (threadIdx.x < 64) zrow[threadIdx.x] = 0.f;
  }
}

__device__ __forceinline__ void split_store(float v, ushort_t* hi, ushort_t* lo, size_t i) {
  ushort_t h = f2bs(v);
  hi[i] = h;
  lo[i] = f2bs(v - bs2f(h));
}

__global__ void k_w1(const float* __restrict__ src, ushort_t* __restrict__ h,
                     ushort_t* __restrict__ l) {
  int i = blockIdx.x * 256 + threadIdx.x;
  if (i >= 16384) return;
  int oc = i >> 6, k = i & 63;
  float v = 0.f;
  if (k < 48) {
    int tap = k / 3, ic = k - 3 * tap;
    v = src[(oc * 3 + ic) * 16 + tap];
  }
  split_store(v, h, l, i);
}

__global__ void k_w2(const float* __restrict__ src, ushort_t* __restrict__ h,
                     ushort_t* __restrict__ l) {
  int i = blockIdx.x * 256 + threadIdx.x;  // 1048576
  int oc = i >> 12, k = i & 4095;
  int tap = k >> 8, ic = k & 255;
  split_store(src[(oc * 256 + ic) * 16 + tap], h, l, i);
}

__global__ void k_w3e(const float* __restrict__ src, ushort_t* __restrict__ h,
                      ushort_t* __restrict__ l) {
  int i = blockIdx.x * 256 + threadIdx.x;  // 1179648
  int rb = i / 589824, r2 = i - rb * 589824;
  int oc = r2 / 2304, k = r2 - oc * 2304;
  int r9 = k >> 8, ic = k & 255;
  split_store(src[((rb * 256 + oc) * 256 + ic) * 9 + r9], h, l, i);
}

__global__ void k_w3d(const float* __restrict__ src, ushort_t* __restrict__ h) {
  int i = blockIdx.x * 256 + threadIdx.x;  // 1179648
  int rb = i / 589824, r2 = i - rb * 589824;
  int oc = r2 / 2304, k = r2 - oc * 2304;
  int r9 = k >> 8, ic = k & 255;
  h[i] = f2bs(src[((rb * 256 + oc) * 256 + ic) * 9 + r9]);
}

__global__ void k_w1re(const float* __restrict__ src, ushort_t* __restrict__ h,
                       ushort_t* __restrict__ l) {
  int i = blockIdx.x * 256 + threadIdx.x;  // 131072
  split_store(src[i], h, l, i);
}

__global__ void k_w1rd(const float* __restrict__ src, ushort_t* __restrict__ h) {
  int i = blockIdx.x * 256 + threadIdx.x;  // 131072
  h[i] = f2bs(src[i]);
}

__global__ void k_wd1(const float* __restrict__ src, ushort_t* __restrict__ dst) {
  int i = blockIdx.x * 256 + threadIdx.x;  // 1048576
  int cls = i >> 18, r2 = i & 262143;
  int oc = r2 >> 10, k = r2 & 1023;
  int tap = k >> 8, ic = k & 255;
  int s = tap >> 1, sx = tap & 1;
  int py = cls >> 1, px = cls & 1;
  int ky = py + 2 - 2 * s, kx = px + 2 - 2 * sx;
  dst[i] = f2bs(src[(ic * 256 + oc) * 16 + ky * 4 + kx]);
}

__global__ void k_prep_dec2(const float* __restrict__ src, float* __restrict__ dst) {
  int i = blockIdx.x * 256 + threadIdx.x;
  if (i >= 12288) return;
  int kyx = i & 15;
  int r = i >> 4;
  int oc = r % 3;
  int ic = r / 3;
  dst[(ic * 16 + kyx) * 3 + oc] = src[i];
}

__global__ void k_enorm(const float* __restrict__ emb, float* __restrict__ enorm) {
  int e = blockIdx.x * 64 + threadIdx.x;
  if (e >= 512) return;
  float s = 0.f;
  for (int c = 0; c < 256; ++c) {
    float v = emb[e * 256 + c];
    s += v * v;
  }
  enorm[e] = s;
}

__global__ void k_build_a1(const float* __restrict__ x, ushort_t* __restrict__ h,
                           ushort_t* __restrict__ l) {
  int i = blockIdx.x * 256 + threadIdx.x;  // 4194304
  int t1 = i >> 6, k = i & 63;
  float v = 0.f;
  if (k < 48) {
    int tap = k / 3, ic = k - 3 * tap;
    int n = t1 >> 8, oy = (t1 >> 4) & 15, ox = t1 & 15;
    int ky = tap >> 2, kx = tap & 3;
    int iy = 2 * oy - 1 + ky, ix = 2 * ox - 1 + kx;
    if ((unsigned)iy < 32u && (unsigned)ix < 32u)
      v = x[((n * 3 + ic) * 32 + iy) * 32 + ix];
  }
  split_store(v, h, l, i);
}

// ---------------- MFMA GEMM ----------------
// BM=128, BN=64. 4 LDS planes (A:2x8KB, B:2x4KB), chunk-major 16-row sets
// (conflict-free ds_read_b128). Per barrier window:
//   STYLE 1 (split): planes = Ah,Al,Bh,Bl @ k0 (BK=32) -> AhBh+AlBh+AhBl = 24 MFMA
//   STYLE 0 (plain): planes = Ah@k0, Ah@k0+32, Bh@k0, Bh@k0+32 (BK=64) -> 16 MFMA
// MODE: 0=direct A, 1=conv2 im2col (16x16 grid), 2=res3 3x3 im2col (8x8),
//       3=deconv1 tap (8x8, cls=blockIdx.z)
// EPI:  1=relu->f32, 2=res+relu->f32, 3=deconv1 remap relu->bf16, 4=relu->split bf16
template <int MODE, int EPI, int STYLE>
__global__ __launch_bounds__(256) void k_gemm(const ushort_t* __restrict__ Ah,
                                              const ushort_t* __restrict__ Al,
                                              const ushort_t* __restrict__ Bh,
                                              const ushort_t* __restrict__ Bl, int K,
                                              const float* __restrict__ bias,
                                              const float* __restrict__ res,
                                              float* __restrict__ outf,
                                              ushort_t* __restrict__ outb,
                                              ushort_t* __restrict__ outb2,
                                              const ushort_t* __restrict__ zrow) {
  __shared__ __align__(16) ushort_t A0[128 * 32];
  __shared__ __align__(16) ushort_t A1s[128 * 32];
  __shared__ __align__(16) ushort_t B0[64 * 32];
  __shared__ __align__(16) ushort_t B1[64 * 32];
  const int t = threadIdx.x;
  const int w = t >> 6, l = t & 63;
  const int M0 = blockIdx.x * 128, N0 = blockIdx.y * 64;
  int py = 0, px = 0;
  const ushort_t* Bb = Bh;
  if (MODE == 3) {
    int cls = blockIdx.z;
    py = cls >> 1;
    px = cls & 1;
    Bb = Bh + (size_t)cls * 262144;
  }
  // staging lane mapping (chunk-major): lane l -> row l&15 of its 16-row set, chunk l>>4
  const int srow = l & 15, chunk = l >> 4;
  const int tok1 = M0 + w * 32 + srow, tok2 = tok1 + 16;
  const int bR = N0 + w * 16 + srow;
  // reader coords
  const int fr = l & 15, quad = l >> 4;
  const int m_off = (w & 1) * 64, n_off = (w >> 1) * 32;
  const int mset = (m_off >> 4), nset = (n_off >> 4);

  f32x4 acc[4][2];
#pragma unroll
  for (int i = 0; i < 4; ++i)
#pragma unroll
    for (int j = 0; j < 2; ++j) acc[i][j] = (f32x4){0.f, 0.f, 0.f, 0.f};

  ushort_t* a0d1 = A0 + w * 1024;
  ushort_t* a0d2 = a0d1 + 512;
  ushort_t* a1d1 = A1s + w * 1024;
  ushort_t* a1d2 = a1d1 + 512;
  ushort_t* b0d = B0 + w * 512;
  ushort_t* b1d = B1 + w * 512;

  const int n1 = tok1 >> 6, oy1 = (tok1 >> 3) & 7, ox1 = tok1 & 7;
  const int n2 = tok2 >> 6, oy2 = (tok2 >> 3) & 7, ox2 = tok2 & 7;
  const ushort_t* zp = zrow + chunk * 8;

  const int STEP = (STYLE == 1) ? 32 : 64;
  for (int k0 = 0; k0 < K; k0 += STEP) {
    const ushort_t *p1, *p2, *q1, *q2;
    if (MODE == 0) {
      size_t o1 = (size_t)tok1 * K + k0 + chunk * 8;
      size_t o2 = (size_t)tok2 * K + k0 + chunk * 8;
      p1 = Ah + o1;
      p2 = Ah + o2;
      q1 = (STYLE == 1) ? Al + o1 : Ah + o1 + 32;
      q2 = (STYLE == 1) ? Al + o2 : Ah + o2 + 32;
    } else {
      int tap = k0 >> 8, kin = (k0 & 255) + chunk * 8;
      int iy1, ix1, iy2, ix2;
      unsigned lim;
      if (MODE == 1) {
        int ky = tap >> 2, kx = tap & 3;
        iy1 = 2 * oy1 - 1 + ky; ix1 = 2 * ox1 - 1 + kx;
        iy2 = 2 * oy2 - 1 + ky; ix2 = 2 * ox2 - 1 + kx;
        lim = 16u;
      } else if (MODE == 2) {
        int ky = tap / 3, kx = tap - ky * 3;
        iy1 = oy1 - 1 + ky; ix1 = ox1 - 1 + kx;
        iy2 = oy2 - 1 + ky; ix2 = ox2 - 1 + kx;
        lim = 8u;
      } else {
        int s = tap >> 1, sx = tap & 1;
        iy1 = oy1 + s - py; ix1 = ox1 + sx - px;
        iy2 = oy2 + s - py; ix2 = ox2 + sx - px;
        lim = 8u;
      }
      bool v1 = ((unsigned)iy1 < lim && (unsigned)ix1 < lim);
      bool v2 = ((unsigned)iy2 < lim && (unsigned)ix2 < lim);
      size_t r1, r2;
      if (MODE == 1) {
        r1 = (size_t)(((n1 << 8) + (iy1 << 4) + ix1)) << 8;
        r2 = (size_t)(((n2 << 8) + (iy2 << 4) + ix2)) << 8;
      } else {
        r1 = (size_t)(((n1 << 6) + (iy1 << 3) + ix1)) << 8;
        r2 = (size_t)(((n2 << 6) + (iy2 << 3) + ix2)) << 8;
      }
      p1 = v1 ? Ah + r1 + kin : zp;
      p2 = v2 ? Ah + r2 + kin : zp;
      if (STYLE == 1) {
        q1 = v1 ? Al + r1 + kin : zp;
        q2 = v2 ? Al + r2 + kin : zp;
      } else {
        q1 = v1 ? Ah + r1 + kin + 32 : zp;
        q2 = v2 ? Ah + r2 + kin + 32 : zp;
      }
    }
    size_t bo = (size_t)bR * K + k0 + chunk * 8;
    glds16(p1, a0d1);
    glds16(p2, a0d2);
    glds16(q1, a1d1);
    glds16(q2, a1d2);
    glds16(Bb + bo, b0d);
    glds16((STYLE == 1) ? (Bl + bo) : (Bb + bo + 32), b1d);
    __syncthreads();
    short8v af0[4], af1[4], bf0[2], bf1[2];
#pragma unroll
    for (int mi = 0; mi < 4; ++mi) {
      af0[mi] = *(const short8v*)(A0 + (mset + mi) * 512 + quad * 128 + fr * 8);
      af1[mi] = *(const short8v*)(A1s + (mset + mi) * 512 + quad * 128 + fr * 8);
    }
#pragma unroll
    for (int nj = 0; nj < 2; ++nj) {
      bf0[nj] = *(const short8v*)(B0 + (nset + nj) * 512 + quad * 128 + fr * 8);
      bf1[nj] = *(const short8v*)(B1 + (nset + nj) * 512 + quad * 128 + fr * 8);
    }
#pragma unroll
    for (int mi = 0; mi < 4; ++mi)
#pragma unroll
      for (int nj = 0; nj < 2; ++nj) {
        acc[mi][nj] =
            __builtin_amdgcn_mfma_f32_16x16x32_bf16(af0[mi], bf0[nj], acc[mi][nj], 0, 0, 0);
        if (STYLE == 1) {
          acc[mi][nj] =
              __builtin_amdgcn_mfma_f32_16x16x32_bf16(af1[mi], bf0[nj], acc[mi][nj], 0, 0, 0);
          acc[mi][nj] =
              __builtin_amdgcn_mfma_f32_16x16x32_bf16(af0[mi], bf1[nj], acc[mi][nj], 0, 0, 0);
        } else {
          acc[mi][nj] =
              __builtin_amdgcn_mfma_f32_16x16x32_bf16(af1[mi], bf1[nj], acc[mi][nj], 0, 0, 0);
        }
      }
    __syncthreads();
  }

#pragma unroll
  for (int mi = 0; mi < 4; ++mi) {
    int mrow = m_off + mi * 16 + (l >> 4) * 4;
#pragma unroll
    for (int nj = 0; nj < 2; ++nj) {
      int col = N0 + n_off + nj * 16 + fr;
      float bv = bias[col];
#pragma unroll
      for (int i = 0; i < 4; ++i) {
        int m = M0 + mrow + i;
        float v = fmaxf(acc[mi][nj][i] + bv, 0.f);
        if (EPI == 1) {
          outf[(size_t)m * 256 + col] = v;
        } else if (EPI == 2) {
          size_t o = (size_t)m * 256 + col;
          outf[o] = res[o] + v;
        } else if (EPI == 3) {
          int nn = m >> 6, jj = (m >> 3) & 7, ii = m & 7;
          int oy = 2 * jj + 1 - py, ox = 2 * ii + 1 - px;
          outb[(size_t)((nn << 8) + oy * 16 + ox) * 256 + col] = f2bs(v);
        } else {  // EPI 4: split bf16
          size_t o = (size_t)m * 256 + col;
          ushort_t h = f2bs(v);
          outb[o] = h;
          outb2[o] = f2bs(v - bs2f(h));
        }
      }
    }
  }
}

// ---------------- fused rmsnorm: per-sample rms + normalize + bf16(split) cast ----
template <int SPLIT>
__global__ void __launch_bounds__(256) k_rmsnorm(const float* __restrict__ in,
                                                 const float* __restrict__ rmsw,
                                                 ushort_t* __restrict__ NBh,
                                                 ushort_t* __restrict__ NBl) {
  __shared__ float sd[256];
  __shared__ float s_scale;
  int n = blockIdx.x, t = threadIdx.x;
  const float* p = in + (size_t)n * 16384;
  float s = 0.f;
  for (int i = t; i < 16384; i += 256) {
    float v = p[i];
    s += v * v;
  }
  sd[t] = s;
  __syncthreads();
  for (int k = 128; k > 0; k >>= 1) {
    if (t < k) sd[t] += sd[t + k];
    __syncthreads();
  }
  if (t == 0) s_scale = 1.0f / sqrtf(sd[0] / 16384.f + 1.1920929e-07f);
  __syncthreads();
  float scale = s_scale;
  ushort_t* oh = NBh + (size_t)n * 16384;
  ushort_t* ol = NBl + (size_t)n * 16384;
  for (int j = 0; j < 64; ++j) {
    int i = j * 256 + t;  // token j (of this sample), channel t
    float v = p[i] * scale * rmsw[t * 64 + j];
    ushort_t h = f2bs(v);
    oh[i] = h;
    if (SPLIT) ol[i] = f2bs(v - bs2f(h));
  }
}

__global__ void __launch_bounds__(256) k_cast(const float* __restrict__ in,
                                              ushort_t* __restrict__ out) {
  int i = blockIdx.x * 256 + threadIdx.x;
  out[i] = f2bs(in[i]);
}

// ---------------- VQ: 16 tokens/block, fp32, emb read directly ----------------
__global__ void __launch_bounds__(256) k_vq(const float* __restrict__ enc,
                                            const float* __restrict__ emb,
                                            const float* __restrict__ enorm,
                                            float* __restrict__ q, float* __restrict__ sse) {
  __shared__ float z[16][256];
  __shared__ float sc[512 * 16];
  __shared__ float bv[16][16];
  __shared__ int bi[16][16];
  __shared__ int idxs[16];
  int T0 = blockIdx.x * 16;
  int t = threadIdx.x;
  for (int j = 0; j < 16; ++j) z[j][t] = enc[(size_t)(T0 + j) * 256 + t];
  __syncthreads();
  float d0[16], d1[16];
#pragma unroll
  for (int j = 0; j < 16; ++j) { d0[j] = 0.f; d1[j] = 0.f; }
  const float4* e0 = (const float4*)(emb + (size_t)t * 256);
  const float4* e1 = (const float4*)(emb + (size_t)(t + 256) * 256);
  for (int c4 = 0; c4 < 64; ++c4) {
    float4 ea = e0[c4];
    float4 eb = e1[c4];
#pragma unroll
    for (int j = 0; j < 16; ++j) {
      float4 zv = *(const float4*)&z[j][c4 * 4];
      d0[j] += zv.x * ea.x + zv.y * ea.y + zv.z * ea.z + zv.w * ea.w;
      d1[j] += zv.x * eb.x + zv.y * eb.y + zv.z * eb.z + zv.w * eb.w;
    }
  }
  float en0 = enorm[t], en1 = enorm[t + 256];
#pragma unroll
  for (int j = 0; j < 16; ++j) {
    sc[t * 16 + j] = en0 - 2.f * d0[j];
    sc[(t + 256) * 16 + j] = en1 - 2.f * d1[j];
  }
  __syncthreads();
  {
    int j = t & 15, chunk = t >> 4;
    float best = 3.4e38f;
    int bidx = 0;
    int c0 = chunk * 32;
    for (int cc = 0; cc < 32; ++cc) {
      float v = sc[(c0 + cc) * 16 + j];
      if (v < best) { best = v; bidx = c0 + cc; }
    }
    bv[chunk][j] = best;
    bi[chunk][j] = bidx;
  }
  __syncthreads();
  if (t < 16) {
    float best = 3.4e38f;
    int bidx = 0;
    for (int c = 0; c < 16; ++c) {
      float v = bv[c][t];
      if (v < best) { best = v; bidx = bi[c][t]; }
    }
    idxs[t] = bidx;
  }
  __syncthreads();
  float sq = 0.f;
  for (int j = 0; j < 16; ++j) {
    float e = emb[(size_t)idxs[j] * 256 + t];
    q[(size_t)(T0 + j) * 256 + t] = e;
    float d = z[j][t] - e;
    sq += d * d;
  }
  __syncthreads();
  sc[t] = sq;
  __syncthreads();
  for (int k = 128; k > 0; k >>= 1) {
    if (t < k) sc[t] += sc[t + k];
    __syncthreads();
  }
  if (t == 0) atomicAdd(sse, sc[0]);
}

// ---------------- deconv2 + reconst loss ----------------
__global__ void __launch_bounds__(256) k_deconv2(const ushort_t* __restrict__ in,
                                                 const float* __restrict__ wT,
                                                 const float* __restrict__ bias,
                                                 const float* __restrict__ x,
                                                 float* __restrict__ dec,
                                                 float* __restrict__ sse) {
  __shared__ float patch[9216];  // [ic=256][s=2][col=18]
  __shared__ float red[768];
  int blk = blockIdx.x;  // 8192 = n*32 + oy
  int oy = blk & 31, n = blk >> 5;
  int t = threadIdx.x;
  int py = (oy + 1) & 1;
  int dy = (oy + 1 - py) >> 1;
  for (int it = 0; it < 36; ++it) {
    int s = it / 18, col = it - s * 18;
    int ix = col - 1, iy = dy - 1 + s;
    float v = 0.f;
    if ((unsigned)iy < 16u && (unsigned)ix < 16u)
      v = bs2f(in[(size_t)((n << 8) + iy * 16 + ix) * 256 + t]);
    patch[(t * 2 + s) * 18 + col] = v;
  }
  __syncthreads();
  int ox = t & 31, g = t >> 5;
  int px = (ox + 1) & 1;
  int dx = (ox + 1 - px) >> 1;
  int k00 = ((py + 2) * 4 + px + 2) * 3;
  int k01 = k00 - 6;
  int k10 = (py * 4 + px + 2) * 3;
  int k11 = k10 - 6;
  float a0 = 0.f, a1 = 0.f, a2 = 0.f;
  for (int ic = g * 32; ic < g * 32 + 32; ++ic) {
    const float* pp = patch + ic * 36;
    float v00 = pp[dx], v01 = pp[dx + 1], v10 = pp[18 + dx], v11 = pp[18 + dx + 1];
    const float* ww = wT + ic * 48;
    a0 += v00 * ww[k00 + 0] + v01 * ww[k01 + 0] + v10 * ww[k10 + 0] + v11 * ww[k11 + 0];
    a1 += v00 * ww[k00 + 1] + v01 * ww[k01 + 1] + v10 * ww[k10 + 1] + v11 * ww[k11 + 1];
    a2 += v00 * ww[k00 + 2] + v01 * ww[k01 + 2] + v10 * ww[k10 + 2] + v11 * ww[k11 + 2];
  }
  red[t * 3 + 0] = a0;
  red[t * 3 + 1] = a1;
  red[t * 3 + 2] = a2;
  __syncthreads();
  float sq = 0.f;
  if (t < 96) {
    int ox2 = t & 31, oc = t >> 5;
    float v = bias[oc];
#pragma unroll
    for (int g2 = 0; g2 < 8; ++g2) v += red[(g2 * 32 + ox2) * 3 + oc];
    int oi = ((n * 3 + oc) * 32 + oy) * 32 + ox2;
    dec[oi] = v;
    float d = v - x[oi];
    sq = d * d;
  }
  __syncthreads();
  red[t] = sq;
  __syncthreads();
  for (int k = 128; k > 0; k >>= 1) {
    if (t < k) red[t] += red[t + k];
    __syncthreads();
  }
  if (t == 0) atomicAdd(sse, red[0]);
}

__global__ void k_final(const float* __restrict__ acc, float* __restrict__ out) {
  if (threadIdx.x == 0 && blockIdx.x == 0) {
    float vq = acc[0] / 4194304.f;
    float rec = acc[1] / 786432.f;
    out[0] = rec + 2.f * vq;
    out[1] = rec;
    out[2] = vq;
    out[3] = vq;
  }
}

extern "C" void kernel_launch(void* const* d_in, const int* in_sizes, int n_in,
                              void* d_out, int out_size, void* d_ws, size_t ws_size,
                              hipStream_t stream) {
  (void)in_sizes; (void)n_in; (void)out_size; (void)ws_size;
  const float* x = (const float*)d_in[0];
  const float* ew1 = (const float*)d_in[1];
  const float* eb1 = (const float*)d_in[2];
  const float* ew2 = (const float*)d_in[3];
  const float* eb2 = (const float*)d_in[4];
  const float* rmsw = (const float*)d_in[5];
  const float* r3w = (const float*)d_in[6];
  const float* r3b = (const float*)d_in[7];
  const float* r1w = (const float*)d_in[8];
  const float* r1b = (const float*)d_in[9];
  const float* emb = (const float*)d_in[10];
  const float* dw1 = (const float*)d_in[11];
  const float* db1 = (const float*)d_in[12];
  const float* dw2 = (const float*)d_in[13];
  const float* db2 = (const float*)d_in[14];
  float* out = (float*)d_out;

  float* wsf = (float*)d_ws;
  float* P = wsf + OFF_P;
  float* enorm = wsf + OFF_ENORM;
  float* wTd2 = wsf + OFF_WTD2;
  float* acc = wsf + OFF_ACC;
  float* zrowf = wsf + OFF_ZROW;
  ushort_t* sb = (ushort_t*)(wsf + OFF_SHORT);
  ushort_t* H1H = sb + SO_H1H;  // conv1 hi; later deconv1 out
  ushort_t* H1L = sb + SO_H1L;  // conv1 lo; later Qf
  float* Qf = (float*)(sb + SO_H1L);
  ushort_t* NBH = sb + SO_NBH;  // also A1h
  ushort_t* NBL = sb + SO_NBL;  // also A1l, QB
  ushort_t* A1H = NBH;
  ushort_t* A1L = NBL;
  ushort_t* QB = NBL;
  ushort_t* W1H = sb + SO_W1H;
  ushort_t* W1L = sb + SO_W1L;
  ushort_t* W2H = sb + SO_W2H;
  ushort_t* W2L = sb + SO_W2L;
  ushort_t* W3EH = sb + SO_W3EH;
  ushort_t* W3EL = sb + SO_W3EL;
  ushort_t* W3D = sb + SO_W3D;
  ushort_t* W1REH = sb + SO_W1REH;
  ushort_t* W1REL = sb + SO_W1REL;
  ushort_t* W1RD = sb + SO_W1RD;
  ushort_t* WD1 = sb + SO_WD1;
  const ushort_t* zrow = (const ushort_t*)zrowf;

  k_zero<<<1, 256, 0, stream>>>(acc, zrowf);

  // weight prep
  k_w1<<<64, 256, 0, stream>>>(ew1, W1H, W1L);
  k_w2<<<4096, 256, 0, stream>>>(ew2, W2H, W2L);
  k_w3e<<<4608, 256, 0, stream>>>(r3w, W3EH, W3EL);
  k_w3d<<<4608, 256, 0, stream>>>(r3w + 2 * 589824, W3D);
  k_w1re<<<512, 256, 0, stream>>>(r1w, W1REH, W1REL);
  k_w1rd<<<512, 256, 0, stream>>>(r1w + 2 * 65536, W1RD);
  k_wd1<<<4096, 256, 0, stream>>>(dw1, WD1);
  k_prep_dec2<<<48, 256, 0, stream>>>(dw2, wTd2);
  k_enorm<<<8, 64, 0, stream>>>(emb, enorm);

  // encoder (split-bf16, fp32-grade)
  k_build_a1<<<16384, 256, 0, stream>>>(x, A1H, A1L);
  k_gemm<0, 4, 1><<<dim3(512, 4), 256, 0, stream>>>(A1H, A1L, W1H, W1L, 64, eb1,
                                                    nullptr, nullptr, H1H, H1L, zrow);
  k_gemm<1, 1, 1><<<dim3(128, 4), 256, 0, stream>>>(H1H, H1L, W2H, W2L, 4096, eb2,
                                                    nullptr, P, nullptr, nullptr, zrow);
  for (int rb = 0; rb < 2; ++rb) {
    k_rmsnorm<1><<<256, 256, 0, stream>>>(P, rmsw + (size_t)(rb * 2 + 0) * 16384, NBH, NBL);
    k_gemm<2, 2, 1><<<dim3(128, 4), 256, 0, stream>>>(
        NBH, NBL, W3EH + (size_t)rb * 589824, W3EL + (size_t)rb * 589824, 2304,
        r3b + rb * 256, P, Qf, nullptr, nullptr, zrow);
    k_rmsnorm<1><<<256, 256, 0, stream>>>(Qf, rmsw + (size_t)(rb * 2 + 1) * 16384, NBH, NBL);
    k_gemm<0, 2, 1><<<dim3(128, 4), 256, 0, stream>>>(
        NBH, NBL, W1REH + (size_t)rb * 65536, W1REL + (size_t)rb * 65536, 256,
        r1b + rb * 256, Qf, P, nullptr, nullptr, zrow);
  }

  // VQ: P (enc) -> Qf (q), sse -> acc[0]
  k_vq<<<1024, 256, 0, stream>>>(P, emb, enorm, Qf, acc + 0);

  // decoder res blocks (plain bf16, BK=64)
  for (int rb = 2; rb < 4; ++rb) {
    k_rmsnorm<0><<<256, 256, 0, stream>>>(Qf, rmsw + (size_t)(rb * 2 + 0) * 16384, NBH, NBL);
    k_gemm<2, 2, 0><<<dim3(128, 4), 256, 0, stream>>>(
        NBH, nullptr, W3D + (size_t)(rb - 2) * 589824, nullptr, 2304,
        r3b + rb * 256, Qf, P, nullptr, nullptr, zrow);
    k_rmsnorm<0><<<256, 256, 0, stream>>>(P, rmsw + (size_t)(rb * 2 + 1) * 16384, NBH, NBL);
    k_gemm<0, 2, 0><<<dim3(128, 4), 256, 0, stream>>>(
        NBH, nullptr, W1RD + (size_t)(rb - 2) * 65536, nullptr, 256,
        r1b + rb * 256, P, Qf, nullptr, nullptr, zrow);
  }

  // deconv1 (4 parity classes) -> H1H region
  k_cast<<<16384, 256, 0, stream>>>(Qf, QB);
  k_gemm<3, 3, 0><<<dim3(128, 4, 4), 256, 0, stream>>>(QB, nullptr, WD1, nullptr, 1024, db1,
                                                       nullptr, nullptr, H1H, nullptr, zrow);

  // deconv2 + reconst loss
  k_deconv2<<<8192, 256, 0, stream>>>(H1H, wTd2, db2, x, out + 4, acc + 1);
  k_final<<<1, 64, 0, stream>>>(acc, out);
}